// Round 1
// baseline (270.705 us; speedup 1.0000x reference)
//
#include <hip/hip_runtime.h>
#include <math.h>

#define NN 512

typedef __attribute__((ext_vector_type(8))) short bf16x8;
typedef __attribute__((ext_vector_type(4))) float f32x4;
typedef __attribute__((ext_vector_type(4))) unsigned int u32x4;

__device__ inline unsigned short f2bf(float f) {
    unsigned u = __builtin_bit_cast(unsigned, f);
    u += 0x7fffu + ((u >> 16) & 1u);   // round-to-nearest-even
    return (unsigned short)(u >> 16);
}
__device__ inline float bf2f(unsigned short h) {
    unsigned u = ((unsigned)h) << 16;
    return __builtin_bit_cast(float, u);
}
__device__ inline unsigned cvtpk_bf16(float lo, float hi) {
    unsigned r;
    asm("v_cvt_pk_bf16_f32 %0, %1, %2" : "=v"(r) : "v"(lo), "v"(hi));
    return r;
}

// Parity-split DCT matrices: Ce[kk][n] = C[2kk][n], Co[kk][n] = C[2kk+1][n], n<256.
__global__ __launch_bounds__(256) void fill_dct_half(unsigned short* __restrict__ Ce,
                                                     unsigned short* __restrict__ Co) {
    int idx = blockIdx.x * 256 + threadIdx.x;     // 0..131071
    int par = idx >> 16;
    int kk = (idx >> 8) & 255;
    int n = idx & 255;
    int k = 2 * kk + par;
    int m = ((2 * n + 1) * k) & 2047;
    float ang = (float)m * 3.0679615757712823e-3f;   // * pi/1024
    float s = (k == 0) ? 0.04419417382415922f : 0.0625f;
    unsigned short v = f2bf(s * cosf(ang));
    if (par) Co[kk * 256 + n] = v; else Ce[kk * 256 + n] = v;
}

#define GLB(p) ((const __attribute__((address_space(1))) unsigned int*)(const void*)(p))
#define LDS(p) ((__attribute__((address_space(3))) unsigned int*)(p))

// Parity-decomposed DCT pass, K=256 (8 K-steps of 32). 128x128 tile, 4 waves.
// R8: latency-targeted restructure of the R7 kernel.
//  - reg-staged LDS side cut 3 bufs -> 2 (combineWrite(kt+1) vs compute(kt)
//    never collide under the per-iter barrier) => LDS 48KB -> 40KB => 4 blocks/CU.
//  - raw-register pipeline deepened to 2 sets: loadRaw(kt+3) at iter kt,
//    consumed by combineWrite(kt+3) at iter kt+2 (~2 iters > HBM latency),
//    so the per-iter implicit vmcnt drain at combineWrite no longer stalls.
//  - counted vmcnt: steady 18 (p1) / 10 (p2); tail 10/6 then 0.
// PASS 1: T'[k][r] = sum_{n<256} (x[r][n] +- x[r][511-n]) * Ce/Co[k'][n]
//         bx<2 even k (+), bx>=2 odd k (-). B=Ce/Co gload_lds; A=X reg-staged.
// PASS 2: Out[q][k] = sum_{r<256} Ce/Co[q'][r] * (T'[k][r] +- T'[k][511-r])
//         by<2 even q (+), by>=2 odd q (-). A=Ce/Co gload_lds; B=T' reg-staged.
template <int PASS>
__global__ __launch_bounds__(256, 4) void gemm_dct(const void* __restrict__ Ap,
                                                   const unsigned short* __restrict__ Ce,
                                                   const unsigned short* __restrict__ Cop,
                                                   void* __restrict__ Outp,
                                                   size_t strideIn, size_t strideOut) {
    const int nwg = (int)gridDim.x;
    const int cpx = nwg >> 3;
    const int bid = (int)blockIdx.x;
    const int nid = (bid & 7) * cpx + (bid >> 3);   // bijective XCD swizzle (nwg%8==0)
    const int bx = nid & 3;
    const int by = (nid >> 2) & 3;
    const int bz = nid >> 4;

    // 40960 B total: reg side 2 bufs (8192 shorts), gload side 3 bufs (12288 shorts).
    __shared__ unsigned short sm[20480];
    unsigned short* const As = sm;                                   // A-operand side
    unsigned short* const Bs = sm + (PASS == 1 ? 8192 : 12288);      // B-operand side
    // pass1: As = reg-staged (2 bufs), Bs = gload (3 bufs)
    // pass2: As = gload (3 bufs),      Bs = reg-staged (2 bufs)

    const int t = threadIdx.x;
    const int lane = t & 63;
    const int wave = t >> 6;
    const int wr = wave >> 1, wc = wave & 1;
    const int lr = lane & 15;
    const int kgx = ((lane >> 4) * 8) ^ (((lr >> 1) & 3) << 3);

    // global_load_lds staging (Ce/Co side), 128x32 tile, pre-swizzled source
    const int srow = t >> 2;
    const int sslot = t & 3;
    const int scol = (sslot ^ ((srow >> 1) & 3)) * 8;

    // reg staging: thread -> (row 0..127, 16-elem half of the 32-col step)
    const int frow = t >> 1;
    const int fhalf = t & 1;
    const int fs0 = fhalf * 2;
    const int fxw = (frow >> 1) & 3;
    const int fslot0 = (fs0 ^ fxw) * 8;
    const int fslot1 = ((fs0 + 1) ^ fxw) * 8;

    const float* Xf = nullptr;
    const unsigned short* Tp = nullptr;
    const unsigned short* Gmat;
    int grow0, sgn, row0, col0;
    if constexpr (PASS == 1) {
        Xf = (const float*)Ap + (size_t)bz * strideIn;
        row0 = by * 128;
        col0 = bx * 128;
        Gmat = (bx < 2) ? Ce : Cop; grow0 = (bx & 1) * 128; sgn = (bx >= 2);
    } else {
        Tp = (const unsigned short*)Ap + (size_t)bz * strideIn;
        col0 = bx * 128;
        row0 = 0;
        Gmat = (by < 2) ? Ce : Cop; grow0 = (by & 1) * 128; sgn = (by >= 2);
    }
    const float sgnf = sgn ? -1.0f : 1.0f;

    f32x4 acc[4][4] = {};

    // depth-2 raw tiles (fwd + mirror), two named sets (static indexing only)
    f32x4 rf0[4], rm0[4], rf1[4], rm1[4];     // pass 1 (fp32)
    bf16x8 gf0[2], gm0[2], gf1[2], gm1[2];    // pass 2 (bf16)

    auto stageG = [&](unsigned short* dst, int buf, int k0) {
        __builtin_amdgcn_global_load_lds(GLB(Gmat + (size_t)(grow0 + srow) * 256 + k0 + scol),
                                         LDS(&dst[buf * 4096 + srow * 32 + sslot * 8]), 16, 0, 0);
        __builtin_amdgcn_global_load_lds(GLB(Gmat + (size_t)(grow0 + 64 + srow) * 256 + k0 + scol),
                                         LDS(&dst[buf * 4096 + (64 + srow) * 32 + sslot * 8]), 16, 0, 0);
    };
    auto lr1 = [&](f32x4 (&rf)[4], f32x4 (&rm)[4], int k0) {
        const float* bfp = Xf + (size_t)(row0 + frow) * NN + k0 + fhalf * 16;
        const float* bmp = Xf + (size_t)(row0 + frow) * NN + (496 - k0 - fhalf * 16);
#pragma unroll
        for (int q = 0; q < 4; ++q) {
            rf[q] = *reinterpret_cast<const f32x4*>(bfp + 4 * q);
            rm[q] = *reinterpret_cast<const f32x4*>(bmp + 4 * q);
        }
    };
    auto cw1 = [&](f32x4 (&rf)[4], f32x4 (&rm)[4], int buf) {
        unsigned p[8];
#pragma unroll
        for (int q = 0; q < 8; ++q) {
            const int j0 = 2 * q, j1 = 2 * q + 1;
            const int r0 = 15 - j0, r1 = 15 - j1;
            float s0 = fmaf(sgnf, rm[r0 >> 2][r0 & 3], rf[j0 >> 2][j0 & 3]);
            float s1 = fmaf(sgnf, rm[r1 >> 2][r1 & 3], rf[j1 >> 2][j1 & 3]);
            p[q] = cvtpk_bf16(s0, s1);
        }
        u32x4 w0 = {p[0], p[1], p[2], p[3]};
        u32x4 w1 = {p[4], p[5], p[6], p[7]};
        *reinterpret_cast<u32x4*>(&As[buf * 4096 + frow * 32 + fslot0]) = w0;
        *reinterpret_cast<u32x4*>(&As[buf * 4096 + frow * 32 + fslot1]) = w1;
    };
    auto lr2 = [&](bf16x8 (&gf)[2], bf16x8 (&gm)[2], int k0) {
        const unsigned short* bfp = Tp + (size_t)(col0 + frow) * NN + k0 + fhalf * 16;
        const unsigned short* bmp = Tp + (size_t)(col0 + frow) * NN + (496 - k0 - fhalf * 16);
        gf[0] = *reinterpret_cast<const bf16x8*>(bfp);
        gf[1] = *reinterpret_cast<const bf16x8*>(bfp + 8);
        gm[0] = *reinterpret_cast<const bf16x8*>(bmp);
        gm[1] = *reinterpret_cast<const bf16x8*>(bmp + 8);
    };
    auto cw2 = [&](bf16x8 (&gf)[2], bf16x8 (&gm)[2], int buf) {
        unsigned p[8];
#pragma unroll
        for (int q = 0; q < 8; ++q) {
            const int j0 = 2 * q, j1 = 2 * q + 1;
            const int r0 = 15 - j0, r1 = 15 - j1;
            float a0 = bf2f((unsigned short)gf[j0 >> 3][j0 & 7]);
            float a1 = bf2f((unsigned short)gf[j1 >> 3][j1 & 7]);
            float b0 = bf2f((unsigned short)gm[r0 >> 3][r0 & 7]);
            float b1 = bf2f((unsigned short)gm[r1 >> 3][r1 & 7]);
            p[q] = cvtpk_bf16(fmaf(sgnf, b0, a0), fmaf(sgnf, b1, a1));
        }
        u32x4 w0 = {p[0], p[1], p[2], p[3]};
        u32x4 w1 = {p[4], p[5], p[6], p[7]};
        *reinterpret_cast<u32x4*>(&Bs[buf * 4096 + frow * 32 + fslot0]) = w0;
        *reinterpret_cast<u32x4*>(&Bs[buf * 4096 + frow * 32 + fslot1]) = w1;
    };
    auto compute = [&](int kt) {
        const int bA = (PASS == 1) ? (kt & 1) : (kt % 3);   // A side: reg(2)/gload(3)
        const int bB = (PASS == 1) ? (kt % 3) : (kt & 1);   // B side: gload(3)/reg(2)
        bf16x8 a[4], b[4];
#pragma unroll
        for (int mi = 0; mi < 4; ++mi)
            a[mi] = *reinterpret_cast<const bf16x8*>(
                &As[bA * 4096 + (wr * 64 + mi * 16 + lr) * 32 + kgx]);
#pragma unroll
        for (int ni = 0; ni < 4; ++ni)
            b[ni] = *reinterpret_cast<const bf16x8*>(
                &Bs[bB * 4096 + (wc * 64 + ni * 16 + lr) * 32 + kgx]);
        __builtin_amdgcn_s_setprio(1);
#pragma unroll
        for (int mi = 0; mi < 4; ++mi)
#pragma unroll
            for (int ni = 0; ni < 4; ++ni)
                acc[mi][ni] = __builtin_amdgcn_mfma_f32_16x16x32_bf16(a[mi], b[ni],
                                                                      acc[mi][ni], 0, 0, 0);
        __builtin_amdgcn_s_setprio(0);
    };

    // ---- prologue: tile0 staged+written; raw tiles 1,2 in flight ----
    if constexpr (PASS == 1) {
        stageG(Bs, 0, 0);
        lr1(rf0, rm0, 0);
        asm volatile("" ::: "memory");      // pin FIFO: tile0 VMEM first
        cw1(rf0, rm0, 0);                   // implicit drain: raw(0) + stage(0)
        stageG(Bs, 1, 32);
        asm volatile("" ::: "memory");      // pin: stage(1) before raw(1)/(2)
        lr1(rf1, rm1, 32);
        lr1(rf0, rm0, 64);
        asm volatile("s_waitcnt lgkmcnt(0)" ::: "memory");
        asm volatile("s_waitcnt vmcnt(18)" ::: "memory");  // tile0 G drained
        __builtin_amdgcn_s_barrier();
    } else {
        stageG(As, 0, 0);
        lr2(gf0, gm0, 0);
        asm volatile("" ::: "memory");
        cw2(gf0, gm0, 0);
        stageG(As, 1, 32);
        asm volatile("" ::: "memory");
        lr2(gf1, gm1, 32);
        lr2(gf0, gm0, 64);
        asm volatile("s_waitcnt lgkmcnt(0)" ::: "memory");
        asm volatile("s_waitcnt vmcnt(10)" ::: "memory");
        __builtin_amdgcn_s_barrier();
    }

    // ---- 8 K-steps, fully unrolled; 1 barrier per step ----
#pragma unroll
    for (int kt = 0; kt < 8; ++kt) {
        if (kt + 1 <= 7) {                  // fold+write tile kt+1 (raw loaded iter kt-2)
            if constexpr (PASS == 1) {
                if ((kt + 1) & 1) cw1(rf1, rm1, 1); else cw1(rf0, rm0, 0);
            } else {
                if ((kt + 1) & 1) cw2(gf1, gm1, 1); else cw2(gf0, gm0, 0);
            }
        }
        if (kt + 2 <= 7)                    // gload tile kt+2 (3-buf side)
            stageG(PASS == 1 ? Bs : As, (kt + 2) % 3, (kt + 2) * 32);
        asm volatile("" ::: "memory");      // pin: stage(kt+2) before raw(kt+3) in FIFO
        if (kt + 3 <= 7) {                  // raw tile kt+3 (2-iter latency cover)
            if constexpr (PASS == 1) {
                if ((kt + 3) & 1) lr1(rf1, rm1, (kt + 3) * 32); else lr1(rf0, rm0, (kt + 3) * 32);
            } else {
                if ((kt + 3) & 1) lr2(gf1, gm1, (kt + 3) * 32); else lr2(gf0, gm0, (kt + 3) * 32);
            }
        }
        compute(kt);
        asm volatile("s_waitcnt lgkmcnt(0)" ::: "memory");
        if (kt <= 4) {
            // outstanding: stage(kt+1)[.] lr(kt+2) stage(kt+2) lr(kt+3) -> retire stage(kt+1)
            if constexpr (PASS == 1) asm volatile("s_waitcnt vmcnt(18)" ::: "memory");
            else                     asm volatile("s_waitcnt vmcnt(10)" ::: "memory");
        } else if (kt == 5) {
            if constexpr (PASS == 1) asm volatile("s_waitcnt vmcnt(10)" ::: "memory");
            else                     asm volatile("s_waitcnt vmcnt(6)" ::: "memory");
        } else if (kt == 6) {
            asm volatile("s_waitcnt vmcnt(0)" ::: "memory");
        }
        if (kt < 7) __builtin_amdgcn_s_barrier();
    }

    // ---- epilogue. C/D frag: row = (lane>>4)*4 + reg, col = lane&15 ----
    if constexpr (PASS == 1) {
        // LDS-staged transposed store with parity row permutation.
        unsigned short* T = (unsigned short*)Outp + (size_t)bz * strideOut;
        __syncthreads();
#pragma unroll
        for (int mi = 0; mi < 4; ++mi)
#pragma unroll
            for (int ni = 0; ni < 4; ++ni) {
                int gr = wr * 64 + mi * 16 + (lane >> 4) * 4;   // local r
                int gc = wc * 64 + ni * 16 + lr;                // local k'
                ushort4 v;
                v.x = f2bf(acc[mi][ni][0]);
                v.y = f2bf(acc[mi][ni][1]);
                v.z = f2bf(acc[mi][ni][2]);
                v.w = f2bf(acc[mi][ni][3]);
                *reinterpret_cast<ushort4*>(&sm[gc * 132 + gr]) = v;
            }
        __syncthreads();
#pragma unroll
        for (int it = 0; it < 8; ++it) {
            int gcr = wave * 32 + it * 4 + (lane >> 4);         // local k'
            int physRow = (bx & 1) * 256 + 2 * gcr + (bx >> 1); // natural k
            int cb = lr * 8;
            u32x4 d = *reinterpret_cast<const u32x4*>(&sm[gcr * 132 + cb]);
            *reinterpret_cast<u32x4*>(&T[(size_t)physRow * NN + row0 + cb]) = d;
        }
    } else {
        float* O = (float*)Outp + (size_t)bz * strideOut;
#pragma unroll
        for (int mi = 0; mi < 4; ++mi)
#pragma unroll
            for (int ni = 0; ni < 4; ++ni) {
                int gc = col0 + wc * 64 + ni * 16 + lr;         // natural k col
#pragma unroll
                for (int rr = 0; rr < 4; ++rr) {
                    int grl = wr * 64 + mi * 16 + (lane >> 4) * 4 + rr;  // local q'
                    int ih = (by & 1) * 128 + grl;
                    int q = 2 * ih + (by >> 1);                 // natural q row
                    O[(size_t)q * NN + gc] = acc[mi][ni][rr];
                }
            }
    }
}

extern "C" void kernel_launch(void* const* d_in, const int* in_sizes, int n_in,
                              void* d_out, int out_size, void* d_ws, size_t ws_size,
                              hipStream_t stream) {
    const float* x = (const float*)d_in[0];
    float* out = (float*)d_out;

    const int imgs = in_sizes[0] / (NN * NN);            // 96
    const size_t imgElems = (size_t)NN * NN;             // 262144
    const size_t imgB16 = imgElems * 2;                  // 512 KB

    unsigned short* Ce = (unsigned short*)d_ws;          // 128 KB
    unsigned short* Co = Ce + 65536;                     // 128 KB
    unsigned short* Tb = Co + 65536;                     // T' buffers

    long long budget = (long long)ws_size - 262144;
    int maxchunk = (int)(budget / (long long)imgB16);
    if (maxchunk < 1) maxchunk = 1;
    if (maxchunk > imgs) maxchunk = imgs;

    hipLaunchKernelGGL(fill_dct_half, dim3(512), dim3(256), 0, stream, Ce, Co);

    for (int i0 = 0; i0 < imgs; i0 += maxchunk) {
        int c = imgs - i0 < maxchunk ? imgs - i0 : maxchunk;
        hipLaunchKernelGGL((gemm_dct<1>), dim3(16 * c), dim3(256), 0, stream,
                           x + (size_t)i0 * imgElems, Ce, Co, Tb, imgElems, imgElems);
        hipLaunchKernelGGL((gemm_dct<2>), dim3(16 * c), dim3(256), 0, stream,
                           Tb, Ce, Co, out + (size_t)i0 * imgElems, imgElems, imgElems);
    }
}

// Round 2
// 139.927 us; speedup vs baseline: 1.9346x; 1.9346x over previous
//
#include <hip/hip_runtime.h>
#include <math.h>

#define NN 512

typedef __attribute__((ext_vector_type(8))) short bf16x8;
typedef __attribute__((ext_vector_type(4))) float f32x4;
typedef __attribute__((ext_vector_type(4))) unsigned int u32x4;

__device__ inline unsigned short f2bf(float f) {
    unsigned u = __builtin_bit_cast(unsigned, f);
    u += 0x7fffu + ((u >> 16) & 1u);   // round-to-nearest-even
    return (unsigned short)(u >> 16);
}
__device__ inline float bf2f(unsigned short h) {
    unsigned u = ((unsigned)h) << 16;
    return __builtin_bit_cast(float, u);
}
__device__ inline unsigned cvtpk_bf16(float lo, float hi) {
    unsigned r;
    asm("v_cvt_pk_bf16_f32 %0, %1, %2" : "=v"(r) : "v"(lo), "v"(hi));
    return r;
}

// Parity-split DCT matrices: Ce[kk][n] = C[2kk][n], Co[kk][n] = C[2kk+1][n], n<256.
__global__ __launch_bounds__(256) void fill_dct_half(unsigned short* __restrict__ Ce,
                                                     unsigned short* __restrict__ Co) {
    int idx = blockIdx.x * 256 + threadIdx.x;     // 0..131071
    int par = idx >> 16;
    int kk = (idx >> 8) & 255;
    int n = idx & 255;
    int k = 2 * kk + par;
    int m = ((2 * n + 1) * k) & 2047;
    float ang = (float)m * 3.0679615757712823e-3f;   // * pi/1024
    float s = (k == 0) ? 0.04419417382415922f : 0.0625f;
    unsigned short v = f2bf(s * cosf(ang));
    if (par) Co[kk * 256 + n] = v; else Ce[kk * 256 + n] = v;
}

#define GLB(p) ((const __attribute__((address_space(1))) unsigned int*)(const void*)(p))
#define LDS(p) ((__attribute__((address_space(3))) unsigned int*)(p))

// Parity-decomposed DCT pass, K=256 (8 K-steps of 32). 128x128 tile, 4 waves.
// R9: R8's depth-2 raw pipeline, spill-fixed.
//  - R8 post-mortem: __launch_bounds__(256,4) capped unified RF at 128 regs
//    while demand is ~172 (64 acc + ~108 arch) -> ~44 spilled VGPRs ->
//    232/435 MB scratch traffic. Fix: bounds (256,3) -> cap ~168, demand
//    ~4 over -> allocator remats/spills only cold values.
//  - reg-staged LDS side 2 bufs, gload side 3 bufs (40KB; 3 blocks/CU now
//    register-limited, LDS has slack).
//  - raw pipeline depth 2: loadRaw(kt+3) at iter kt, consumed by
//    combineWrite at iter kt+2 (~2 iters > HBM latency) -> the implicit
//    vmcnt drain at combineWrite stops serializing a full RTT per K-step.
//  - counted vmcnt: steady 18 (p1) / 10 (p2); tail 10/6 then 0.
// PASS 1: T'[k][r] = sum_{n<256} (x[r][n] +- x[r][511-n]) * Ce/Co[k'][n]
//         bx<2 even k (+), bx>=2 odd k (-). B=Ce/Co gload_lds; A=X reg-staged.
// PASS 2: Out[q][k] = sum_{r<256} Ce/Co[q'][r] * (T'[k][r] +- T'[k][511-r])
//         by<2 even q (+), by>=2 odd q (-). A=Ce/Co gload_lds; B=T' reg-staged.
template <int PASS>
__global__ __launch_bounds__(256, 3) void gemm_dct(const void* __restrict__ Ap,
                                                   const unsigned short* __restrict__ Ce,
                                                   const unsigned short* __restrict__ Cop,
                                                   void* __restrict__ Outp,
                                                   size_t strideIn, size_t strideOut) {
    const int nwg = (int)gridDim.x;
    const int cpx = nwg >> 3;
    const int bid = (int)blockIdx.x;
    const int nid = (bid & 7) * cpx + (bid >> 3);   // bijective XCD swizzle (nwg%8==0)
    const int bx = nid & 3;
    const int by = (nid >> 2) & 3;
    const int bz = nid >> 4;

    // 40960 B total: reg side 2 bufs (8192 shorts), gload side 3 bufs (12288 shorts).
    __shared__ unsigned short sm[20480];
    unsigned short* const As = sm;                                   // A-operand side
    unsigned short* const Bs = sm + (PASS == 1 ? 8192 : 12288);      // B-operand side
    // pass1: As = reg-staged (2 bufs), Bs = gload (3 bufs)
    // pass2: As = gload (3 bufs),      Bs = reg-staged (2 bufs)

    const int t = threadIdx.x;
    const int lane = t & 63;
    const int wave = t >> 6;
    const int wr = wave >> 1, wc = wave & 1;
    const int lr = lane & 15;
    const int kgx = ((lane >> 4) * 8) ^ (((lr >> 1) & 3) << 3);

    // global_load_lds staging (Ce/Co side), 128x32 tile, pre-swizzled source
    const int srow = t >> 2;
    const int sslot = t & 3;
    const int scol = (sslot ^ ((srow >> 1) & 3)) * 8;

    // reg staging: thread -> (row 0..127, 16-elem half of the 32-col step)
    const int frow = t >> 1;
    const int fhalf = t & 1;
    const int fs0 = fhalf * 2;
    const int fxw = (frow >> 1) & 3;
    const int fslot0 = (fs0 ^ fxw) * 8;
    const int fslot1 = ((fs0 + 1) ^ fxw) * 8;

    const float* Xf = nullptr;
    const unsigned short* Tp = nullptr;
    const unsigned short* Gmat;
    int grow0, sgn, row0, col0;
    if constexpr (PASS == 1) {
        Xf = (const float*)Ap + (size_t)bz * strideIn;
        row0 = by * 128;
        col0 = bx * 128;
        Gmat = (bx < 2) ? Ce : Cop; grow0 = (bx & 1) * 128; sgn = (bx >= 2);
    } else {
        Tp = (const unsigned short*)Ap + (size_t)bz * strideIn;
        col0 = bx * 128;
        row0 = 0;
        Gmat = (by < 2) ? Ce : Cop; grow0 = (by & 1) * 128; sgn = (by >= 2);
    }
    const float sgnf = sgn ? -1.0f : 1.0f;

    f32x4 acc[4][4] = {};

    // depth-2 raw tiles (fwd + mirror), two named sets (static indexing only)
    f32x4 rf0[4], rm0[4], rf1[4], rm1[4];     // pass 1 (fp32)
    bf16x8 gf0[2], gm0[2], gf1[2], gm1[2];    // pass 2 (bf16)

    auto stageG = [&](unsigned short* dst, int buf, int k0) {
        __builtin_amdgcn_global_load_lds(GLB(Gmat + (size_t)(grow0 + srow) * 256 + k0 + scol),
                                         LDS(&dst[buf * 4096 + srow * 32 + sslot * 8]), 16, 0, 0);
        __builtin_amdgcn_global_load_lds(GLB(Gmat + (size_t)(grow0 + 64 + srow) * 256 + k0 + scol),
                                         LDS(&dst[buf * 4096 + (64 + srow) * 32 + sslot * 8]), 16, 0, 0);
    };
    auto lr1 = [&](f32x4 (&rf)[4], f32x4 (&rm)[4], int k0) {
        const float* bfp = Xf + (size_t)(row0 + frow) * NN + k0 + fhalf * 16;
        const float* bmp = Xf + (size_t)(row0 + frow) * NN + (496 - k0 - fhalf * 16);
#pragma unroll
        for (int q = 0; q < 4; ++q) {
            rf[q] = *reinterpret_cast<const f32x4*>(bfp + 4 * q);
            rm[q] = *reinterpret_cast<const f32x4*>(bmp + 4 * q);
        }
    };
    auto cw1 = [&](f32x4 (&rf)[4], f32x4 (&rm)[4], int buf) {
        unsigned p[8];
#pragma unroll
        for (int q = 0; q < 8; ++q) {
            const int j0 = 2 * q, j1 = 2 * q + 1;
            const int r0 = 15 - j0, r1 = 15 - j1;
            float s0 = fmaf(sgnf, rm[r0 >> 2][r0 & 3], rf[j0 >> 2][j0 & 3]);
            float s1 = fmaf(sgnf, rm[r1 >> 2][r1 & 3], rf[j1 >> 2][j1 & 3]);
            p[q] = cvtpk_bf16(s0, s1);
        }
        u32x4 w0 = {p[0], p[1], p[2], p[3]};
        u32x4 w1 = {p[4], p[5], p[6], p[7]};
        *reinterpret_cast<u32x4*>(&As[buf * 4096 + frow * 32 + fslot0]) = w0;
        *reinterpret_cast<u32x4*>(&As[buf * 4096 + frow * 32 + fslot1]) = w1;
    };
    auto lr2 = [&](bf16x8 (&gf)[2], bf16x8 (&gm)[2], int k0) {
        const unsigned short* bfp = Tp + (size_t)(col0 + frow) * NN + k0 + fhalf * 16;
        const unsigned short* bmp = Tp + (size_t)(col0 + frow) * NN + (496 - k0 - fhalf * 16);
        gf[0] = *reinterpret_cast<const bf16x8*>(bfp);
        gf[1] = *reinterpret_cast<const bf16x8*>(bfp + 8);
        gm[0] = *reinterpret_cast<const bf16x8*>(bmp);
        gm[1] = *reinterpret_cast<const bf16x8*>(bmp + 8);
    };
    auto cw2 = [&](bf16x8 (&gf)[2], bf16x8 (&gm)[2], int buf) {
        unsigned p[8];
#pragma unroll
        for (int q = 0; q < 8; ++q) {
            const int j0 = 2 * q, j1 = 2 * q + 1;
            const int r0 = 15 - j0, r1 = 15 - j1;
            float a0 = bf2f((unsigned short)gf[j0 >> 3][j0 & 7]);
            float a1 = bf2f((unsigned short)gf[j1 >> 3][j1 & 7]);
            float b0 = bf2f((unsigned short)gm[r0 >> 3][r0 & 7]);
            float b1 = bf2f((unsigned short)gm[r1 >> 3][r1 & 7]);
            p[q] = cvtpk_bf16(fmaf(sgnf, b0, a0), fmaf(sgnf, b1, a1));
        }
        u32x4 w0 = {p[0], p[1], p[2], p[3]};
        u32x4 w1 = {p[4], p[5], p[6], p[7]};
        *reinterpret_cast<u32x4*>(&Bs[buf * 4096 + frow * 32 + fslot0]) = w0;
        *reinterpret_cast<u32x4*>(&Bs[buf * 4096 + frow * 32 + fslot1]) = w1;
    };
    auto compute = [&](int kt) {
        const int bA = (PASS == 1) ? (kt & 1) : (kt % 3);   // A side: reg(2)/gload(3)
        const int bB = (PASS == 1) ? (kt % 3) : (kt & 1);   // B side: gload(3)/reg(2)
        bf16x8 a[4], b[4];
#pragma unroll
        for (int mi = 0; mi < 4; ++mi)
            a[mi] = *reinterpret_cast<const bf16x8*>(
                &As[bA * 4096 + (wr * 64 + mi * 16 + lr) * 32 + kgx]);
#pragma unroll
        for (int ni = 0; ni < 4; ++ni)
            b[ni] = *reinterpret_cast<const bf16x8*>(
                &Bs[bB * 4096 + (wc * 64 + ni * 16 + lr) * 32 + kgx]);
        __builtin_amdgcn_s_setprio(1);
#pragma unroll
        for (int mi = 0; mi < 4; ++mi)
#pragma unroll
            for (int ni = 0; ni < 4; ++ni)
                acc[mi][ni] = __builtin_amdgcn_mfma_f32_16x16x32_bf16(a[mi], b[ni],
                                                                      acc[mi][ni], 0, 0, 0);
        __builtin_amdgcn_s_setprio(0);
    };

    // ---- prologue: tile0 staged+written; raw tiles 1,2 in flight ----
    if constexpr (PASS == 1) {
        stageG(Bs, 0, 0);
        lr1(rf0, rm0, 0);
        asm volatile("" ::: "memory");      // pin FIFO: tile0 VMEM first
        cw1(rf0, rm0, 0);                   // implicit drain: raw(0) + stage(0)
        stageG(Bs, 1, 32);
        asm volatile("" ::: "memory");      // pin: stage(1) before raw(1)/(2)
        lr1(rf1, rm1, 32);
        lr1(rf0, rm0, 64);
        asm volatile("s_waitcnt lgkmcnt(0)" ::: "memory");
        asm volatile("s_waitcnt vmcnt(18)" ::: "memory");  // tile0 G drained
        __builtin_amdgcn_s_barrier();
    } else {
        stageG(As, 0, 0);
        lr2(gf0, gm0, 0);
        asm volatile("" ::: "memory");
        cw2(gf0, gm0, 0);
        stageG(As, 1, 32);
        asm volatile("" ::: "memory");
        lr2(gf1, gm1, 32);
        lr2(gf0, gm0, 64);
        asm volatile("s_waitcnt lgkmcnt(0)" ::: "memory");
        asm volatile("s_waitcnt vmcnt(10)" ::: "memory");
        __builtin_amdgcn_s_barrier();
    }

    // ---- 8 K-steps, fully unrolled; 1 barrier per step ----
#pragma unroll
    for (int kt = 0; kt < 8; ++kt) {
        if (kt + 1 <= 7) {                  // fold+write tile kt+1 (raw loaded iter kt-2)
            if constexpr (PASS == 1) {
                if ((kt + 1) & 1) cw1(rf1, rm1, 1); else cw1(rf0, rm0, 0);
            } else {
                if ((kt + 1) & 1) cw2(gf1, gm1, 1); else cw2(gf0, gm0, 0);
            }
        }
        if (kt + 2 <= 7)                    // gload tile kt+2 (3-buf side)
            stageG(PASS == 1 ? Bs : As, (kt + 2) % 3, (kt + 2) * 32);
        asm volatile("" ::: "memory");      // pin: stage(kt+2) before raw(kt+3) in FIFO
        if (kt + 3 <= 7) {                  // raw tile kt+3 (2-iter latency cover)
            if constexpr (PASS == 1) {
                if ((kt + 3) & 1) lr1(rf1, rm1, (kt + 3) * 32); else lr1(rf0, rm0, (kt + 3) * 32);
            } else {
                if ((kt + 3) & 1) lr2(gf1, gm1, (kt + 3) * 32); else lr2(gf0, gm0, (kt + 3) * 32);
            }
        }
        compute(kt);
        asm volatile("s_waitcnt lgkmcnt(0)" ::: "memory");
        if (kt <= 4) {
            // outstanding: stage(kt+1)[.] lr(kt+2) stage(kt+2) lr(kt+3) -> retire stage(kt+1)
            if constexpr (PASS == 1) asm volatile("s_waitcnt vmcnt(18)" ::: "memory");
            else                     asm volatile("s_waitcnt vmcnt(10)" ::: "memory");
        } else if (kt == 5) {
            if constexpr (PASS == 1) asm volatile("s_waitcnt vmcnt(10)" ::: "memory");
            else                     asm volatile("s_waitcnt vmcnt(6)" ::: "memory");
        } else if (kt == 6) {
            asm volatile("s_waitcnt vmcnt(0)" ::: "memory");
        }
        if (kt < 7) __builtin_amdgcn_s_barrier();
    }

    // ---- epilogue. C/D frag: row = (lane>>4)*4 + reg, col = lane&15 ----
    if constexpr (PASS == 1) {
        // LDS-staged transposed store with parity row permutation.
        unsigned short* T = (unsigned short*)Outp + (size_t)bz * strideOut;
        __syncthreads();
#pragma unroll
        for (int mi = 0; mi < 4; ++mi)
#pragma unroll
            for (int ni = 0; ni < 4; ++ni) {
                int gr = wr * 64 + mi * 16 + (lane >> 4) * 4;   // local r
                int gc = wc * 64 + ni * 16 + lr;                // local k'
                ushort4 v;
                v.x = f2bf(acc[mi][ni][0]);
                v.y = f2bf(acc[mi][ni][1]);
                v.z = f2bf(acc[mi][ni][2]);
                v.w = f2bf(acc[mi][ni][3]);
                *reinterpret_cast<ushort4*>(&sm[gc * 132 + gr]) = v;
            }
        __syncthreads();
#pragma unroll
        for (int it = 0; it < 8; ++it) {
            int gcr = wave * 32 + it * 4 + (lane >> 4);         // local k'
            int physRow = (bx & 1) * 256 + 2 * gcr + (bx >> 1); // natural k
            int cb = lr * 8;
            u32x4 d = *reinterpret_cast<const u32x4*>(&sm[gcr * 132 + cb]);
            *reinterpret_cast<u32x4*>(&T[(size_t)physRow * NN + row0 + cb]) = d;
        }
    } else {
        float* O = (float*)Outp + (size_t)bz * strideOut;
#pragma unroll
        for (int mi = 0; mi < 4; ++mi)
#pragma unroll
            for (int ni = 0; ni < 4; ++ni) {
                int gc = col0 + wc * 64 + ni * 16 + lr;         // natural k col
#pragma unroll
                for (int rr = 0; rr < 4; ++rr) {
                    int grl = wr * 64 + mi * 16 + (lane >> 4) * 4 + rr;  // local q'
                    int ih = (by & 1) * 128 + grl;
                    int q = 2 * ih + (by >> 1);                 // natural q row
                    O[(size_t)q * NN + gc] = acc[mi][ni][rr];
                }
            }
    }
}

extern "C" void kernel_launch(void* const* d_in, const int* in_sizes, int n_in,
                              void* d_out, int out_size, void* d_ws, size_t ws_size,
                              hipStream_t stream) {
    const float* x = (const float*)d_in[0];
    float* out = (float*)d_out;

    const int imgs = in_sizes[0] / (NN * NN);            // 96
    const size_t imgElems = (size_t)NN * NN;             // 262144
    const size_t imgB16 = imgElems * 2;                  // 512 KB

    unsigned short* Ce = (unsigned short*)d_ws;          // 128 KB
    unsigned short* Co = Ce + 65536;                     // 128 KB
    unsigned short* Tb = Co + 65536;                     // T' buffers

    long long budget = (long long)ws_size - 262144;
    int maxchunk = (int)(budget / (long long)imgB16);
    if (maxchunk < 1) maxchunk = 1;
    if (maxchunk > imgs) maxchunk = imgs;

    hipLaunchKernelGGL(fill_dct_half, dim3(512), dim3(256), 0, stream, Ce, Co);

    for (int i0 = 0; i0 < imgs; i0 += maxchunk) {
        int c = imgs - i0 < maxchunk ? imgs - i0 : maxchunk;
        hipLaunchKernelGGL((gemm_dct<1>), dim3(16 * c), dim3(256), 0, stream,
                           x + (size_t)i0 * imgElems, Ce, Co, Tb, imgElems, imgElems);
        hipLaunchKernelGGL((gemm_dct<2>), dim3(16 * c), dim3(256), 0, stream,
                           Tb, Ce, Co, out + (size_t)i0 * imgElems, imgElems, imgElems);
    }
}

// Round 3
// 78.481 us; speedup vs baseline: 3.4493x; 1.7830x over previous
//
#include <hip/hip_runtime.h>
#include <math.h>

#define NN 512

typedef __attribute__((ext_vector_type(8))) short bf16x8;
typedef __attribute__((ext_vector_type(4))) float f32x4;
typedef __attribute__((ext_vector_type(4))) unsigned int u32x4;

__device__ inline unsigned short f2bf(float f) {
    unsigned u = __builtin_bit_cast(unsigned, f);
    u += 0x7fffu + ((u >> 16) & 1u);   // round-to-nearest-even
    return (unsigned short)(u >> 16);
}
__device__ inline float bf2f(unsigned short h) {
    unsigned u = ((unsigned)h) << 16;
    return __builtin_bit_cast(float, u);
}
__device__ inline unsigned cvtpk_bf16(float lo, float hi) {
    unsigned r;
    asm("v_cvt_pk_bf16_f32 %0, %1, %2" : "=v"(r) : "v"(lo), "v"(hi));
    return r;
}

// Parity-split DCT matrices: Ce[kk][n] = C[2kk][n], Co[kk][n] = C[2kk+1][n], n<256.
__global__ __launch_bounds__(256) void fill_dct_half(unsigned short* __restrict__ Ce,
                                                     unsigned short* __restrict__ Co) {
    int idx = blockIdx.x * 256 + threadIdx.x;     // 0..131071
    int par = idx >> 16;
    int kk = (idx >> 8) & 255;
    int n = idx & 255;
    int k = 2 * kk + par;
    int m = ((2 * n + 1) * k) & 2047;
    float ang = (float)m * 3.0679615757712823e-3f;   // * pi/1024
    float s = (k == 0) ? 0.04419417382415922f : 0.0625f;
    unsigned short v = f2bf(s * cosf(ang));
    if (par) Co[kk * 256 + n] = v; else Ce[kk * 256 + n] = v;
}

#define GLB(p) ((const __attribute__((address_space(1))) unsigned int*)(const void*)(p))
#define LDS(p) ((__attribute__((address_space(3))) unsigned int*)(p))

// Parity-decomposed DCT pass, K=256 (8 K-steps of 32). 128x128 tile, 4 waves.
// R10: R9's depth-2 raw pipeline with the register cap actually sized to fit.
//  - R8 (cap 128) and R9 (cap 168) both spilled the raw-tile arrays
//    (demand ~173: 64 acc + 64 raw + ~45 misc); spill traffic 435 -> 196 MB
//    tracked the cap shortfall. Fix: __launch_bounds__(256, 2) -> cap 256.
//    Spill structurally impossible; occupancy cap 2 blocks/CU == R7's
//    MEASURED effective occupancy (24.8% ~= 8 waves), so ~no TLP loss.
//  - reg-staged LDS side 2 bufs, gload side 3 bufs (40KB).
//  - raw pipeline depth 2: loadRaw(kt+3) at iter kt, consumed by
//    combineWrite at iter kt+2 (~2 iters > RTT) -> no serialized RTT/K-step.
//  - counted vmcnt: steady 18 (p1) / 10 (p2); tail 10/6 then 0.
// PASS 1: T'[k][r] = sum_{n<256} (x[r][n] +- x[r][511-n]) * Ce/Co[k'][n]
//         bx<2 even k (+), bx>=2 odd k (-). B=Ce/Co gload_lds; A=X reg-staged.
// PASS 2: Out[q][k] = sum_{r<256} Ce/Co[q'][r] * (T'[k][r] +- T'[k][511-r])
//         by<2 even q (+), by>=2 odd q (-). A=Ce/Co gload_lds; B=T' reg-staged.
template <int PASS>
__global__ __launch_bounds__(256, 2) void gemm_dct(const void* __restrict__ Ap,
                                                   const unsigned short* __restrict__ Ce,
                                                   const unsigned short* __restrict__ Cop,
                                                   void* __restrict__ Outp,
                                                   size_t strideIn, size_t strideOut) {
    const int nwg = (int)gridDim.x;
    const int cpx = nwg >> 3;
    const int bid = (int)blockIdx.x;
    const int nid = (bid & 7) * cpx + (bid >> 3);   // bijective XCD swizzle (nwg%8==0)
    const int bx = nid & 3;
    const int by = (nid >> 2) & 3;
    const int bz = nid >> 4;

    // 40960 B total: reg side 2 bufs (8192 shorts), gload side 3 bufs (12288 shorts).
    __shared__ unsigned short sm[20480];
    unsigned short* const As = sm;                                   // A-operand side
    unsigned short* const Bs = sm + (PASS == 1 ? 8192 : 12288);      // B-operand side
    // pass1: As = reg-staged (2 bufs), Bs = gload (3 bufs)
    // pass2: As = gload (3 bufs),      Bs = reg-staged (2 bufs)

    const int t = threadIdx.x;
    const int lane = t & 63;
    const int wave = t >> 6;
    const int wr = wave >> 1, wc = wave & 1;
    const int lr = lane & 15;
    const int kgx = ((lane >> 4) * 8) ^ (((lr >> 1) & 3) << 3);

    // global_load_lds staging (Ce/Co side), 128x32 tile, pre-swizzled source
    const int srow = t >> 2;
    const int sslot = t & 3;
    const int scol = (sslot ^ ((srow >> 1) & 3)) * 8;

    // reg staging: thread -> (row 0..127, 16-elem half of the 32-col step)
    const int frow = t >> 1;
    const int fhalf = t & 1;
    const int fs0 = fhalf * 2;
    const int fxw = (frow >> 1) & 3;
    const int fslot0 = (fs0 ^ fxw) * 8;
    const int fslot1 = ((fs0 + 1) ^ fxw) * 8;

    const float* Xf = nullptr;
    const unsigned short* Tp = nullptr;
    const unsigned short* Gmat;
    int grow0, sgn, row0, col0;
    if constexpr (PASS == 1) {
        Xf = (const float*)Ap + (size_t)bz * strideIn;
        row0 = by * 128;
        col0 = bx * 128;
        Gmat = (bx < 2) ? Ce : Cop; grow0 = (bx & 1) * 128; sgn = (bx >= 2);
    } else {
        Tp = (const unsigned short*)Ap + (size_t)bz * strideIn;
        col0 = bx * 128;
        row0 = 0;
        Gmat = (by < 2) ? Ce : Cop; grow0 = (by & 1) * 128; sgn = (by >= 2);
    }
    const float sgnf = sgn ? -1.0f : 1.0f;

    f32x4 acc[4][4] = {};

    // depth-2 raw tiles (fwd + mirror), two named sets (static indexing only)
    f32x4 rf0[4], rm0[4], rf1[4], rm1[4];     // pass 1 (fp32)
    bf16x8 gf0[2], gm0[2], gf1[2], gm1[2];    // pass 2 (bf16)

    auto stageG = [&](unsigned short* dst, int buf, int k0) {
        __builtin_amdgcn_global_load_lds(GLB(Gmat + (size_t)(grow0 + srow) * 256 + k0 + scol),
                                         LDS(&dst[buf * 4096 + srow * 32 + sslot * 8]), 16, 0, 0);
        __builtin_amdgcn_global_load_lds(GLB(Gmat + (size_t)(grow0 + 64 + srow) * 256 + k0 + scol),
                                         LDS(&dst[buf * 4096 + (64 + srow) * 32 + sslot * 8]), 16, 0, 0);
    };
    auto lr1 = [&](f32x4 (&rf)[4], f32x4 (&rm)[4], int k0) {
        const float* bfp = Xf + (size_t)(row0 + frow) * NN + k0 + fhalf * 16;
        const float* bmp = Xf + (size_t)(row0 + frow) * NN + (496 - k0 - fhalf * 16);
#pragma unroll
        for (int q = 0; q < 4; ++q) {
            rf[q] = *reinterpret_cast<const f32x4*>(bfp + 4 * q);
            rm[q] = *reinterpret_cast<const f32x4*>(bmp + 4 * q);
        }
    };
    auto cw1 = [&](f32x4 (&rf)[4], f32x4 (&rm)[4], int buf) {
        unsigned p[8];
#pragma unroll
        for (int q = 0; q < 8; ++q) {
            const int j0 = 2 * q, j1 = 2 * q + 1;
            const int r0 = 15 - j0, r1 = 15 - j1;
            float s0 = fmaf(sgnf, rm[r0 >> 2][r0 & 3], rf[j0 >> 2][j0 & 3]);
            float s1 = fmaf(sgnf, rm[r1 >> 2][r1 & 3], rf[j1 >> 2][j1 & 3]);
            p[q] = cvtpk_bf16(s0, s1);
        }
        u32x4 w0 = {p[0], p[1], p[2], p[3]};
        u32x4 w1 = {p[4], p[5], p[6], p[7]};
        *reinterpret_cast<u32x4*>(&As[buf * 4096 + frow * 32 + fslot0]) = w0;
        *reinterpret_cast<u32x4*>(&As[buf * 4096 + frow * 32 + fslot1]) = w1;
    };
    auto lr2 = [&](bf16x8 (&gf)[2], bf16x8 (&gm)[2], int k0) {
        const unsigned short* bfp = Tp + (size_t)(col0 + frow) * NN + k0 + fhalf * 16;
        const unsigned short* bmp = Tp + (size_t)(col0 + frow) * NN + (496 - k0 - fhalf * 16);
        gf[0] = *reinterpret_cast<const bf16x8*>(bfp);
        gf[1] = *reinterpret_cast<const bf16x8*>(bfp + 8);
        gm[0] = *reinterpret_cast<const bf16x8*>(bmp);
        gm[1] = *reinterpret_cast<const bf16x8*>(bmp + 8);
    };
    auto cw2 = [&](bf16x8 (&gf)[2], bf16x8 (&gm)[2], int buf) {
        unsigned p[8];
#pragma unroll
        for (int q = 0; q < 8; ++q) {
            const int j0 = 2 * q, j1 = 2 * q + 1;
            const int r0 = 15 - j0, r1 = 15 - j1;
            float a0 = bf2f((unsigned short)gf[j0 >> 3][j0 & 7]);
            float a1 = bf2f((unsigned short)gf[j1 >> 3][j1 & 7]);
            float b0 = bf2f((unsigned short)gm[r0 >> 3][r0 & 7]);
            float b1 = bf2f((unsigned short)gm[r1 >> 3][r1 & 7]);
            p[q] = cvtpk_bf16(fmaf(sgnf, b0, a0), fmaf(sgnf, b1, a1));
        }
        u32x4 w0 = {p[0], p[1], p[2], p[3]};
        u32x4 w1 = {p[4], p[5], p[6], p[7]};
        *reinterpret_cast<u32x4*>(&Bs[buf * 4096 + frow * 32 + fslot0]) = w0;
        *reinterpret_cast<u32x4*>(&Bs[buf * 4096 + frow * 32 + fslot1]) = w1;
    };
    auto compute = [&](int kt) {
        const int bA = (PASS == 1) ? (kt & 1) : (kt % 3);   // A side: reg(2)/gload(3)
        const int bB = (PASS == 1) ? (kt % 3) : (kt & 1);   // B side: gload(3)/reg(2)
        bf16x8 a[4], b[4];
#pragma unroll
        for (int mi = 0; mi < 4; ++mi)
            a[mi] = *reinterpret_cast<const bf16x8*>(
                &As[bA * 4096 + (wr * 64 + mi * 16 + lr) * 32 + kgx]);
#pragma unroll
        for (int ni = 0; ni < 4; ++ni)
            b[ni] = *reinterpret_cast<const bf16x8*>(
                &Bs[bB * 4096 + (wc * 64 + ni * 16 + lr) * 32 + kgx]);
        __builtin_amdgcn_s_setprio(1);
#pragma unroll
        for (int mi = 0; mi < 4; ++mi)
#pragma unroll
            for (int ni = 0; ni < 4; ++ni)
                acc[mi][ni] = __builtin_amdgcn_mfma_f32_16x16x32_bf16(a[mi], b[ni],
                                                                      acc[mi][ni], 0, 0, 0);
        __builtin_amdgcn_s_setprio(0);
    };

    // ---- prologue: tile0 staged+written; raw tiles 1,2 in flight ----
    if constexpr (PASS == 1) {
        stageG(Bs, 0, 0);
        lr1(rf0, rm0, 0);
        asm volatile("" ::: "memory");      // pin FIFO: tile0 VMEM first
        cw1(rf0, rm0, 0);                   // implicit drain: raw(0) + stage(0)
        stageG(Bs, 1, 32);
        asm volatile("" ::: "memory");      // pin: stage(1) before raw(1)/(2)
        lr1(rf1, rm1, 32);
        lr1(rf0, rm0, 64);
        asm volatile("s_waitcnt lgkmcnt(0)" ::: "memory");
        asm volatile("s_waitcnt vmcnt(18)" ::: "memory");  // tile0 G drained
        __builtin_amdgcn_s_barrier();
    } else {
        stageG(As, 0, 0);
        lr2(gf0, gm0, 0);
        asm volatile("" ::: "memory");
        cw2(gf0, gm0, 0);
        stageG(As, 1, 32);
        asm volatile("" ::: "memory");
        lr2(gf1, gm1, 32);
        lr2(gf0, gm0, 64);
        asm volatile("s_waitcnt lgkmcnt(0)" ::: "memory");
        asm volatile("s_waitcnt vmcnt(10)" ::: "memory");
        __builtin_amdgcn_s_barrier();
    }

    // ---- 8 K-steps, fully unrolled; 1 barrier per step ----
#pragma unroll
    for (int kt = 0; kt < 8; ++kt) {
        if (kt + 1 <= 7) {                  // fold+write tile kt+1 (raw loaded iter kt-2)
            if constexpr (PASS == 1) {
                if ((kt + 1) & 1) cw1(rf1, rm1, 1); else cw1(rf0, rm0, 0);
            } else {
                if ((kt + 1) & 1) cw2(gf1, gm1, 1); else cw2(gf0, gm0, 0);
            }
        }
        if (kt + 2 <= 7)                    // gload tile kt+2 (3-buf side)
            stageG(PASS == 1 ? Bs : As, (kt + 2) % 3, (kt + 2) * 32);
        asm volatile("" ::: "memory");      // pin: stage(kt+2) before raw(kt+3) in FIFO
        if (kt + 3 <= 7) {                  // raw tile kt+3 (2-iter latency cover)
            if constexpr (PASS == 1) {
                if ((kt + 3) & 1) lr1(rf1, rm1, (kt + 3) * 32); else lr1(rf0, rm0, (kt + 3) * 32);
            } else {
                if ((kt + 3) & 1) lr2(gf1, gm1, (kt + 3) * 32); else lr2(gf0, gm0, (kt + 3) * 32);
            }
        }
        compute(kt);
        asm volatile("s_waitcnt lgkmcnt(0)" ::: "memory");
        if (kt <= 4) {
            // outstanding: stage(kt+1)[.] lr(kt+2) stage(kt+2) lr(kt+3) -> retire stage(kt+1)
            if constexpr (PASS == 1) asm volatile("s_waitcnt vmcnt(18)" ::: "memory");
            else                     asm volatile("s_waitcnt vmcnt(10)" ::: "memory");
        } else if (kt == 5) {
            if constexpr (PASS == 1) asm volatile("s_waitcnt vmcnt(10)" ::: "memory");
            else                     asm volatile("s_waitcnt vmcnt(6)" ::: "memory");
        } else if (kt == 6) {
            asm volatile("s_waitcnt vmcnt(0)" ::: "memory");
        }
        if (kt < 7) __builtin_amdgcn_s_barrier();
    }

    // ---- epilogue. C/D frag: row = (lane>>4)*4 + reg, col = lane&15 ----
    if constexpr (PASS == 1) {
        // LDS-staged transposed store with parity row permutation.
        unsigned short* T = (unsigned short*)Outp + (size_t)bz * strideOut;
        __syncthreads();
#pragma unroll
        for (int mi = 0; mi < 4; ++mi)
#pragma unroll
            for (int ni = 0; ni < 4; ++ni) {
                int gr = wr * 64 + mi * 16 + (lane >> 4) * 4;   // local r
                int gc = wc * 64 + ni * 16 + lr;                // local k'
                ushort4 v;
                v.x = f2bf(acc[mi][ni][0]);
                v.y = f2bf(acc[mi][ni][1]);
                v.z = f2bf(acc[mi][ni][2]);
                v.w = f2bf(acc[mi][ni][3]);
                *reinterpret_cast<ushort4*>(&sm[gc * 132 + gr]) = v;
            }
        __syncthreads();
#pragma unroll
        for (int it = 0; it < 8; ++it) {
            int gcr = wave * 32 + it * 4 + (lane >> 4);         // local k'
            int physRow = (bx & 1) * 256 + 2 * gcr + (bx >> 1); // natural k
            int cb = lr * 8;
            u32x4 d = *reinterpret_cast<const u32x4*>(&sm[gcr * 132 + cb]);
            *reinterpret_cast<u32x4*>(&T[(size_t)physRow * NN + row0 + cb]) = d;
        }
    } else {
        float* O = (float*)Outp + (size_t)bz * strideOut;
#pragma unroll
        for (int mi = 0; mi < 4; ++mi)
#pragma unroll
            for (int ni = 0; ni < 4; ++ni) {
                int gc = col0 + wc * 64 + ni * 16 + lr;         // natural k col
#pragma unroll
                for (int rr = 0; rr < 4; ++rr) {
                    int grl = wr * 64 + mi * 16 + (lane >> 4) * 4 + rr;  // local q'
                    int ih = (by & 1) * 128 + grl;
                    int q = 2 * ih + (by >> 1);                 // natural q row
                    O[(size_t)q * NN + gc] = acc[mi][ni][rr];
                }
            }
    }
}

extern "C" void kernel_launch(void* const* d_in, const int* in_sizes, int n_in,
                              void* d_out, int out_size, void* d_ws, size_t ws_size,
                              hipStream_t stream) {
    const float* x = (const float*)d_in[0];
    float* out = (float*)d_out;

    const int imgs = in_sizes[0] / (NN * NN);            // 96
    const size_t imgElems = (size_t)NN * NN;             // 262144
    const size_t imgB16 = imgElems * 2;                  // 512 KB

    unsigned short* Ce = (unsigned short*)d_ws;          // 128 KB
    unsigned short* Co = Ce + 65536;                     // 128 KB
    unsigned short* Tb = Co + 65536;                     // T' buffers

    long long budget = (long long)ws_size - 262144;
    int maxchunk = (int)(budget / (long long)imgB16);
    if (maxchunk < 1) maxchunk = 1;
    if (maxchunk > imgs) maxchunk = imgs;

    hipLaunchKernelGGL(fill_dct_half, dim3(512), dim3(256), 0, stream, Ce, Co);

    for (int i0 = 0; i0 < imgs; i0 += maxchunk) {
        int c = imgs - i0 < maxchunk ? imgs - i0 : maxchunk;
        hipLaunchKernelGGL((gemm_dct<1>), dim3(16 * c), dim3(256), 0, stream,
                           x + (size_t)i0 * imgElems, Ce, Co, Tb, imgElems, imgElems);
        hipLaunchKernelGGL((gemm_dct<2>), dim3(16 * c), dim3(256), 0, stream,
                           Tb, Ce, Co, out + (size_t)i0 * imgElems, imgElems, imgElems);
    }
}